// Round 9
// baseline (87.249 us; speedup 1.0000x reference)
//
#include <hip/hip_runtime.h>
#include <math.h>

// One wave per ray, 4 rays/block. R8-verified skeleton + two changes:
// (1) FINE MLP in packed fp16: layer-1 v_pk_fma_f16/v_pk_max_f16 on 8-wide
//     f16 vectors, layer-2 v_dot2_f32_f16 (fp32 accumulator). Coarse MLP
//     stays f32 (it feeds the CDF -> discontinuous sample placement).
//     W2 staged once per block as f16 pairs (first barrier -> __syncthreads);
//     A/B staged per wave as f16 alongside the f32 copies.
// (2) v_rcp_f32 replaces precise division in sigmoid / tt / 1/norm
//     (rel err ~1e-6 << 0.12 tolerance). pdf division stays exact (CDF path).
// Scans, CDF, sampling, LDS-single-source-of-truth merge: identical to R8.

#define RAYS   8192
#define NEARP  2.0f
#define FARP   6.0f
#define EPS_T  1e-10f
#define EPS_W  1e-5f
#define F32EPS 1.1920929e-7f

typedef float v2f __attribute__((ext_vector_type(2)));
typedef _Float16 h2 __attribute__((ext_vector_type(2)));
typedef _Float16 h8 __attribute__((ext_vector_type(8)));

__device__ __forceinline__ v2f mk2(float a, float b) { v2f r; r.x = a; r.y = b; return r; }
__device__ __forceinline__ v2f pfma(v2f a, v2f b, v2f c) { return __builtin_elementwise_fma(a, b, c); }
__device__ __forceinline__ v2f pmax0(v2f a) { return __builtin_elementwise_max(a, mk2(0.f, 0.f)); }
__device__ __forceinline__ h8 hfma(h8 a, h8 b, h8 c) { return __builtin_elementwise_fma(a, b, c); }
__device__ __forceinline__ h8 hmax0(h8 a) { h8 z = {0,0,0,0,0,0,0,0}; return __builtin_elementwise_max(a, z); }
__device__ __forceinline__ h2 hpair(h8 v, int k) {
    h2 r; r.x = v[2 * k]; r.y = v[2 * k + 1]; return r;
}
__device__ __forceinline__ float fdot2(h2 a, h2 b, float c) {
    return __builtin_amdgcn_fdot2(a, b, c, false);
}
__device__ __forceinline__ float frcp(float x) { return __builtin_amdgcn_rcpf(x); }

__device__ __forceinline__ float zc(int i) {
    const float t = (float)i * (1.0f / 63.0f);
    return NEARP * (1.0f - t) + FARP * t;
}
__device__ __forceinline__ float sigm(float x) { return frcp(1.f + __expf(-x)); }

// intra-wave LDS sync (wave64 lockstep)
__device__ __forceinline__ void wsync() {
    __asm__ __volatile__("s_waitcnt lgkmcnt(0)" ::: "memory");
    __builtin_amdgcn_wave_barrier();
}

__global__ __launch_bounds__(256) void nerf_kernel(
    const float* __restrict__ ro, const float* __restrict__ rd,
    const float* __restrict__ W1, const float* __restrict__ b1,
    const float* __restrict__ W2, const float* __restrict__ b2,
    float* __restrict__ out)
{
    __shared__ __align__(16) float sA[4][64];
    __shared__ __align__(16) float sB[4][64];
    __shared__ __align__(16) _Float16 sAh[4][64];
    __shared__ __align__(16) _Float16 sBh[4][64];
    __shared__ __align__(16) _Float16 sW2h[256];   // [n][h]: pair p holds (W2[2p][n], W2[2p+1][n])
    __shared__ float sZc [4][64];    // coarse z grid (single source of truth for merge)
    __shared__ float sZs [4][128];   // fine z samples (sorted)
    __shared__ float sZf [4][192];   // merged z
    __shared__ __align__(16) char sPool[4][192 * 16];  // sCdf (early) / sVal (late)

    const int tid  = threadIdx.x;
    const int w    = tid >> 6;
    const int lane = tid & 63;
    const int ray  = blockIdx.x * 4 + w;

    float*  sCdfw = (float*)&sPool[w][0];    // 63 floats used, dead after sampling
    float4* sValw = (float4*)&sPool[w][0];   // 192 float4, live from merge on

    // ---- block-shared W2 f16 pair staging ----
    if (tid < 128) {
        const int n = tid >> 5, p = tid & 31;
        sW2h[n * 64 + 2 * p]     = (_Float16)W2[(2 * p) * 4 + n];
        sW2h[n * 64 + 2 * p + 1] = (_Float16)W2[(2 * p + 1) * 4 + n];
    }

    const float ox = ro[ray * 3 + 0], oy = ro[ray * 3 + 1], oz = ro[ray * 3 + 2];
    const float dx = rd[ray * 3 + 0], dy = rd[ray * 3 + 1], dz = rd[ray * 3 + 2];
    const float norm = sqrtf(dx * dx + dy * dy + dz * dz);
    const float inv  = frcp(norm);
    const float vx = dx * inv, vy = dy * inv, vz = dz * inv;

    // ---- per-ray A/B precompute: lane h (f32 + f16 copies) ----
    {
        const float w10 = W1[lane],       w11 = W1[64 + lane],  w12 = W1[128 + lane];
        const float w13 = W1[192 + lane], w14 = W1[256 + lane], w15 = W1[320 + lane];
        float A = b1[lane];
        A = fmaf(vz, w15, A); A = fmaf(vy, w14, A); A = fmaf(vx, w13, A);
        A = fmaf(oz, w12, A); A = fmaf(oy, w11, A); A = fmaf(ox, w10, A);
        const float B = fmaf(dx, w10, fmaf(dy, w11, dz * w12));
        sA[w][lane] = A; sB[w][lane] = B;
        sAh[w][lane] = (_Float16)A; sBh[w][lane] = (_Float16)B;
    }
    __syncthreads();   // covers per-wave A/B and block-shared sW2h

    const float4* W2v = (const float4*)W2;
    const float bb0 = b2[0], bb1 = b2[1], bb2 = b2[2], bb3 = b2[3];

    // ---------------- coarse pass (f32 — feeds the CDF) ----------------
    const float z = zc(lane);
    sZc[w][lane] = z;
    const v2f zz = mk2(z, z);
    v2f o01 = mk2(bb0, bb1), o23 = mk2(bb2, bb3);
#pragma unroll 4
    for (int i = 0; i < 16; ++i) {
        const float4 a4 = ((const float4*)sA[w])[i];
        const float4 b4 = ((const float4*)sB[w])[i];
        const float4 q0 = W2v[4 * i + 0], q1 = W2v[4 * i + 1];
        const float4 q2 = W2v[4 * i + 2], q3 = W2v[4 * i + 3];
        const v2f hL = pmax0(pfma(zz, mk2(b4.x, b4.y), mk2(a4.x, a4.y)));
        const v2f hH = pmax0(pfma(zz, mk2(b4.z, b4.w), mk2(a4.z, a4.w)));
        o01 = pfma(mk2(hL.x, hL.x), mk2(q0.x, q0.y), o01);
        o23 = pfma(mk2(hL.x, hL.x), mk2(q0.z, q0.w), o23);
        o01 = pfma(mk2(hL.y, hL.y), mk2(q1.x, q1.y), o01);
        o23 = pfma(mk2(hL.y, hL.y), mk2(q1.z, q1.w), o23);
        o01 = pfma(mk2(hH.x, hH.x), mk2(q2.x, q2.y), o01);
        o23 = pfma(mk2(hH.x, hH.x), mk2(q2.z, q2.w), o23);
        o01 = pfma(mk2(hH.y, hH.y), mk2(q3.x, q3.y), o01);
        o23 = pfma(mk2(hH.y, hH.y), mk2(q3.z, q3.w), o23);
    }
    const float r   = sigm(o01.x), g = sigm(o01.y), bl = sigm(o23.x);
    const float sig = fmaxf(o23.y, 0.f);

    // volrender (coarse)
    const float znext = __shfl_down(z, 1);                 // lane63 unused
    const float dist  = (znext - z) * norm;
    const float alpha = (lane < 63) ? (1.f - __expf(-sig * dist)) : 1.f;
    const float vfac  = 1.f - alpha + EPS_T;
    float p = vfac;
#pragma unroll
    for (int off = 1; off < 64; off <<= 1) {               // inclusive product scan
        const float q = __shfl_up(p, off);
        if (lane >= off) p *= q;
    }
    float excl = __shfl_up(p, 1);
    if (lane == 0) excl = 1.f;
    const float wgt = alpha * excl;

    // acc == 1 + O(64*EPS_T) (last alpha forced 1) -> white-bkgd term ~0
    float sr = wgt * r, sg = wgt * g, sb = wgt * bl, sd = wgt * z;
#pragma unroll
    for (int m = 1; m < 64; m <<= 1) {
        sr += __shfl_xor(sr, m); sg += __shfl_xor(sg, m);
        sb += __shfl_xor(sb, m); sd += __shfl_xor(sd, m);
    }

    // ---------------- inverse-CDF sampling ----------------
    const float wmraw = __shfl_down(wgt, 1);
    const float wmv   = (lane < 62) ? wmraw : 0.f;          // weights[:,1:-1], 62 bins
    float wsum = wmv;
#pragma unroll
    for (int m = 1; m < 64; m <<= 1) wsum += __shfl_xor(wsum, m);
    const float pad  = fmaxf(0.f, EPS_W - wsum);
    const float wadj = wmv + pad * (1.0f / 62.0f);
    const float wsp  = wsum + pad;
    const float pdf  = (lane < 62) ? (wadj / wsp) : 0.f;    // exact div: CDF path
    float ps = pdf;
#pragma unroll
    for (int off = 1; off < 64; off <<= 1) {               // inclusive sum scan
        const float q = __shfl_up(ps, off);
        if (lane >= off) ps += q;
    }
    if (lane < 61)  sCdfw[lane + 1] = fminf(1.f, ps);      // cdf[1..61]
    if (lane == 61) sCdfw[0]  = 0.f;
    if (lane == 62) sCdfw[62] = 1.f;
    wsync();

    float zsv[2];
#pragma unroll
    for (int j = 0; j < 2; ++j) {
        const int f = lane * 2 + j;
        const float u = (float)f * ((1.0f - F32EPS) / 127.0f);
        int lo = 0, hi = 62;                               // cdf[0]=0<=u < 1=cdf[62]
        while (hi - lo > 1) {
            const int mid = (lo + hi) >> 1;
            if (sCdfw[mid] <= u) lo = mid; else hi = mid;
        }
        const float c0 = sCdfw[lo], c1 = sCdfw[lo + 1];
        const float den = c1 - c0;
        float tt = (den > 0.f) ? (u - c0) * frcp(den) : 0.f;
        tt = fminf(fmaxf(tt, 0.f), 1.f);
        const float za = zc(lo), zb = zc(lo + 1), zd = zc(lo + 2);
        const float bin0 = 0.5f * (za + zb), bin1 = 0.5f * (zb + zd);
        const float zs = fmaf(tt, bin1 - bin0, bin0);
        zsv[j] = zs;
        sZs[w][f] = zs;
    }
    wsync();   // sCdf reads done; sVal (same pool) may be written after this point

    // ---------------- fresh-sample MLP (2 samples/lane, packed fp16) ----------
    const _Float16 zhA = (_Float16)zsv[0], zhB = (_Float16)zsv[1];
    const h8 z8A = {zhA, zhA, zhA, zhA, zhA, zhA, zhA, zhA};
    const h8 z8B = {zhB, zhB, zhB, zhB, zhB, zhB, zhB, zhB};
    float oA0 = bb0, oA1 = bb1, oA2 = bb2, oA3 = bb3;
    float oB0 = bb0, oB1 = bb1, oB2 = bb2, oB3 = bb3;
    const h8* A8p = (const h8*)sAh[w];
    const h8* B8p = (const h8*)sBh[w];
#pragma unroll 2
    for (int i = 0; i < 8; ++i) {
        const h8 a8 = A8p[i], b8 = B8p[i];
        const h8 hA = hmax0(hfma(z8A, b8, a8));
        const h8 hB = hmax0(hfma(z8B, b8, a8));
        const h8 w0v = ((const h8*)(sW2h +   0))[i];
        const h8 w1v = ((const h8*)(sW2h +  64))[i];
        const h8 w2v = ((const h8*)(sW2h + 128))[i];
        const h8 w3v = ((const h8*)(sW2h + 192))[i];
#pragma unroll
        for (int k = 0; k < 4; ++k) {
            const h2 pA = hpair(hA, k), pB = hpair(hB, k);
            oA0 = fdot2(pA, hpair(w0v, k), oA0);
            oA1 = fdot2(pA, hpair(w1v, k), oA1);
            oA2 = fdot2(pA, hpair(w2v, k), oA2);
            oA3 = fdot2(pA, hpair(w3v, k), oA3);
            oB0 = fdot2(pB, hpair(w0v, k), oB0);
            oB1 = fdot2(pB, hpair(w1v, k), oB1);
            oB2 = fdot2(pB, hpair(w2v, k), oB2);
            oB3 = fdot2(pB, hpair(w3v, k), oB3);
        }
    }
    const float r0s = sigm(oA0), g0s = sigm(oA1), b0s = sigm(oA2), s0 = fmaxf(oA3, 0.f);
    const float r1s = sigm(oB0), g1s = sigm(oB1), b1s = sigm(oB2), s1 = fmaxf(oB3, 0.f);

    // ---------------- merge (LDS single source of truth -> provable bijection) --
    {   // coarse element: pos = lane + count(samples < z); carry coarse MLP values
        int lo = 0, hi = 128;
        while (lo < hi) { const int mid = (lo + hi) >> 1; if (sZs[w][mid] < z) lo = mid + 1; else hi = mid; }
        sZf[w][lane + lo] = z;
        float4 cv; cv.x = r; cv.y = g; cv.z = bl; cv.w = sig;
        sValw[lane + lo] = cv;
    }
#pragma unroll
    for (int j = 0; j < 2; ++j) {   // sample element: pos = idx + count(coarse <= bv)
        const float bv = zsv[j];
        const int f = lane * 2 + j;
        int lo = 0, hi = 64;
        while (lo < hi) { const int mid = (lo + hi) >> 1; if (sZc[w][mid] <= bv) lo = mid + 1; else hi = mid; }
        sZf[w][f + lo] = bv;
        float4 cv;
        if (j == 0) { cv.x = r0s; cv.y = g0s; cv.z = b0s; cv.w = s0; }
        else        { cv.x = r1s; cv.y = g1s; cv.z = b1s; cv.w = s1; }
        sValw[f + lo] = cv;
    }
    wsync();

    // ---------------- fine volrender: 3 positions/lane ----------------
    const float zf0 = sZf[w][3 * lane + 0];
    const float zf1 = sZf[w][3 * lane + 1];
    const float zf2 = sZf[w][3 * lane + 2];
    const float zn2 = sZf[w][min(3 * lane + 3, 191)];      // lane63 value unused
    const float4 c4a = sValw[3 * lane + 0];
    const float4 c4b = sValw[3 * lane + 1];
    const float4 c4c = sValw[3 * lane + 2];

    const float d0 = (zf1 - zf0) * norm, d1 = (zf2 - zf1) * norm, d2 = (zn2 - zf2) * norm;
    const float al0 = 1.f - __expf(-c4a.w * d0);
    const float al1 = 1.f - __expf(-c4b.w * d1);
    const float al2 = (lane < 63) ? (1.f - __expf(-c4c.w * d2)) : 1.f;
    const float t0v = 1.f - al0 + EPS_T, t1v = 1.f - al1 + EPS_T, t2v = 1.f - al2 + EPS_T;

    float lp = t0v * t1v * t2v;
#pragma unroll
    for (int off = 1; off < 64; off <<= 1) {               // product scan of lane products
        const float q = __shfl_up(lp, off);
        if (lane >= off) lp *= q;
    }
    float ex = __shfl_up(lp, 1);
    if (lane == 0) ex = 1.f;
    const float tr1 = ex * t0v, tr2 = tr1 * t1v;
    const float w0 = al0 * ex, w1 = al1 * tr1, w2 = al2 * tr2;

    // fine acc == 1 + O(192*EPS_T) -> white-bkgd term ~0
    float fr = fmaf(w0, c4a.x, fmaf(w1, c4b.x, w2 * c4c.x));
    float fg = fmaf(w0, c4a.y, fmaf(w1, c4b.y, w2 * c4c.y));
    float fb = fmaf(w0, c4a.z, fmaf(w1, c4b.z, w2 * c4c.z));
    float fd = fmaf(w0, zf0,   fmaf(w1, zf1,   w2 * zf2));
#pragma unroll
    for (int m = 1; m < 64; m <<= 1) {
        fr += __shfl_xor(fr, m); fg += __shfl_xor(fg, m);
        fb += __shfl_xor(fb, m); fd += __shfl_xor(fd, m);
    }

    if (lane == 0) {
        float* po = out + (size_t)ray * 8;
        po[0] = sr; po[1] = sg; po[2] = sb; po[3] = sd;
        po[4] = fr; po[5] = fg; po[6] = fb; po[7] = fd;
    }
}

extern "C" void kernel_launch(void* const* d_in, const int* in_sizes, int n_in,
                              void* d_out, int out_size, void* d_ws, size_t ws_size,
                              hipStream_t stream) {
    const float* ro = (const float*)d_in[0];
    const float* rd = (const float*)d_in[1];
    const float* W1 = (const float*)d_in[2];
    const float* b1 = (const float*)d_in[3];
    const float* W2 = (const float*)d_in[4];
    const float* b2 = (const float*)d_in[5];
    float* out = (float*)d_out;
    nerf_kernel<<<dim3(RAYS / 4), dim3(256), 0, stream>>>(ro, rd, W1, b1, W2, b2, out);
}

// Round 10
// 85.192 us; speedup vs baseline: 1.0241x; 1.0241x over previous
//
#include <hip/hip_runtime.h>
#include <math.h>

// One wave per ray, 4 rays/block. R8-verified skeleton (f16 reverted — R9's
// regression was the LDS occupancy cliff: must stay <= 20480 B for 8 blocks/CU)
// + DPP offload of all SMOOTH-path cross-lane ops from the LDS pipe (bpermute)
// to the VALU pipe:
//   (1) 8 output reductions -> DPP ladder (row_shr 1/2/4/8 + row_bcast15/31,
//       result in lane 63),
//   (2) wsum butterfly -> telescoped p0 - p62 (err <= 62*EPS_T, proven),
//   (3) fine transmittance product scan -> DPP inclusive scan.
// CDF-feeding paths (coarse product scan, cdf sum scan, searches, merge) keep
// their bit-exact __shfl/LDS forms — sample placement must not change (R4 lesson).
// Plus R9's proven-safe v_rcp in sigmoid / tt / 1/norm.

#define RAYS   8192
#define NEARP  2.0f
#define FARP   6.0f
#define EPS_T  1e-10f
#define EPS_W  1e-5f
#define F32EPS 1.1920929e-7f

typedef float v2f __attribute__((ext_vector_type(2)));
__device__ __forceinline__ v2f mk2(float a, float b) { v2f r; r.x = a; r.y = b; return r; }
__device__ __forceinline__ v2f pfma(v2f a, v2f b, v2f c) { return __builtin_elementwise_fma(a, b, c); }
__device__ __forceinline__ v2f pmax0(v2f a) { return __builtin_elementwise_max(a, mk2(0.f, 0.f)); }

__device__ __forceinline__ float frcp(float x) { return __builtin_amdgcn_rcpf(x); }

__device__ __forceinline__ float zc(int i) {
    const float t = (float)i * (1.0f / 63.0f);
    return NEARP * (1.0f - t) + FARP * t;
}
__device__ __forceinline__ float sigm(float x) { return frcp(1.f + __expf(-x)); }

// ---- DPP cross-lane (VALU pipe, no LDS) ----
// update_dpp(old, src, ctrl, row_mask, bank_mask, bound_ctrl=false):
// lanes masked off / invalid-source keep `old` (the op identity).
template<int CTRL, int RM>
__device__ __forceinline__ float dppmov(float x, float old) {
    return __int_as_float(__builtin_amdgcn_update_dpp(
        __float_as_int(old), __float_as_int(x), CTRL, RM, 0xf, false));
}
// full 64-lane sum, result valid in lane 63
__device__ __forceinline__ float redsum63(float x) {
    x += dppmov<0x111, 0xf>(x, 0.f);   // row_shr:1
    x += dppmov<0x112, 0xf>(x, 0.f);   // row_shr:2
    x += dppmov<0x114, 0xf>(x, 0.f);   // row_shr:4
    x += dppmov<0x118, 0xf>(x, 0.f);   // row_shr:8
    x += dppmov<0x142, 0xa>(x, 0.f);   // row_bcast:15 -> rows 1,3
    x += dppmov<0x143, 0xc>(x, 0.f);   // row_bcast:31 -> rows 2,3
    return x;
}
// 64-lane inclusive product scan (Hillis-Steele via DPP), valid in all lanes
__device__ __forceinline__ float pscan(float x) {
    x *= dppmov<0x111, 0xf>(x, 1.f);
    x *= dppmov<0x112, 0xf>(x, 1.f);
    x *= dppmov<0x114, 0xf>(x, 1.f);
    x *= dppmov<0x118, 0xf>(x, 1.f);
    x *= dppmov<0x142, 0xa>(x, 1.f);
    x *= dppmov<0x143, 0xc>(x, 1.f);
    return x;
}

// intra-wave LDS sync (wave64 lockstep)
__device__ __forceinline__ void wsync() {
    __asm__ __volatile__("s_waitcnt lgkmcnt(0)" ::: "memory");
    __builtin_amdgcn_wave_barrier();
}

__global__ __launch_bounds__(256) void nerf_kernel(
    const float* __restrict__ ro, const float* __restrict__ rd,
    const float* __restrict__ W1, const float* __restrict__ b1,
    const float* __restrict__ W2, const float* __restrict__ b2,
    float* __restrict__ out)
{
    __shared__ __align__(16) float sA[4][64];
    __shared__ __align__(16) float sB[4][64];
    __shared__ float sZc [4][64];    // coarse z grid (single source of truth for merge)
    __shared__ float sZs [4][128];   // fine z samples (sorted)
    __shared__ float sZf [4][192];   // merged z
    __shared__ __align__(16) char sPool[4][192 * 16];  // sCdf (early) / sVal (late)

    const int tid  = threadIdx.x;
    const int w    = tid >> 6;
    const int lane = tid & 63;
    const int ray  = blockIdx.x * 4 + w;

    float*  sCdfw = (float*)&sPool[w][0];    // 63 floats used, dead after sampling
    float4* sValw = (float4*)&sPool[w][0];   // 192 float4, live from merge on

    const float ox = ro[ray * 3 + 0], oy = ro[ray * 3 + 1], oz = ro[ray * 3 + 2];
    const float dx = rd[ray * 3 + 0], dy = rd[ray * 3 + 1], dz = rd[ray * 3 + 2];
    const float norm = sqrtf(dx * dx + dy * dy + dz * dz);
    const float inv  = frcp(norm);
    const float vx = dx * inv, vy = dy * inv, vz = dz * inv;

    // ---- per-ray A/B precompute: lane h ----
    {
        const float w10 = W1[lane],       w11 = W1[64 + lane],  w12 = W1[128 + lane];
        const float w13 = W1[192 + lane], w14 = W1[256 + lane], w15 = W1[320 + lane];
        float A = b1[lane];
        A = fmaf(vz, w15, A); A = fmaf(vy, w14, A); A = fmaf(vx, w13, A);
        A = fmaf(oz, w12, A); A = fmaf(oy, w11, A); A = fmaf(ox, w10, A);
        const float B = fmaf(dx, w10, fmaf(dy, w11, dz * w12));
        sA[w][lane] = A; sB[w][lane] = B;
    }
    wsync();

    const float4* W2v = (const float4*)W2;
    const float bb0 = b2[0], bb1 = b2[1], bb2 = b2[2], bb3 = b2[3];

    // ---------------- coarse pass (f32 — feeds the CDF) ----------------
    const float z = zc(lane);
    sZc[w][lane] = z;
    const v2f zz = mk2(z, z);
    v2f o01 = mk2(bb0, bb1), o23 = mk2(bb2, bb3);
#pragma unroll 4
    for (int i = 0; i < 16; ++i) {
        const float4 a4 = ((const float4*)sA[w])[i];
        const float4 b4 = ((const float4*)sB[w])[i];
        const float4 q0 = W2v[4 * i + 0], q1 = W2v[4 * i + 1];
        const float4 q2 = W2v[4 * i + 2], q3 = W2v[4 * i + 3];
        const v2f hL = pmax0(pfma(zz, mk2(b4.x, b4.y), mk2(a4.x, a4.y)));
        const v2f hH = pmax0(pfma(zz, mk2(b4.z, b4.w), mk2(a4.z, a4.w)));
        o01 = pfma(mk2(hL.x, hL.x), mk2(q0.x, q0.y), o01);
        o23 = pfma(mk2(hL.x, hL.x), mk2(q0.z, q0.w), o23);
        o01 = pfma(mk2(hL.y, hL.y), mk2(q1.x, q1.y), o01);
        o23 = pfma(mk2(hL.y, hL.y), mk2(q1.z, q1.w), o23);
        o01 = pfma(mk2(hH.x, hH.x), mk2(q2.x, q2.y), o01);
        o23 = pfma(mk2(hH.x, hH.x), mk2(q2.z, q2.w), o23);
        o01 = pfma(mk2(hH.y, hH.y), mk2(q3.x, q3.y), o01);
        o23 = pfma(mk2(hH.y, hH.y), mk2(q3.z, q3.w), o23);
    }
    const float r   = sigm(o01.x), g = sigm(o01.y), bl = sigm(o23.x);
    const float sig = fmaxf(o23.y, 0.f);

    // volrender (coarse) — product scan stays __shfl (feeds the CDF, bit-exact)
    const float znext = __shfl_down(z, 1);                 // lane63 unused
    const float dist  = (znext - z) * norm;
    const float alpha = (lane < 63) ? (1.f - __expf(-sig * dist)) : 1.f;
    const float vfac  = 1.f - alpha + EPS_T;
    float p = vfac;
#pragma unroll
    for (int off = 1; off < 64; off <<= 1) {               // inclusive product scan
        const float q = __shfl_up(p, off);
        if (lane >= off) p *= q;
    }
    float excl = __shfl_up(p, 1);
    if (lane == 0) excl = 1.f;
    const float wgt = alpha * excl;

    // acc == 1 + O(64*EPS_T) (last alpha forced 1) -> white-bkgd term ~0
    // smooth-path reductions on the VALU pipe (DPP), results in lane 63
    const float sr = redsum63(wgt * r);
    const float sg = redsum63(wgt * g);
    const float sb = redsum63(wgt * bl);
    const float sd = redsum63(wgt * z);

    // ---------------- inverse-CDF sampling ----------------
    const float wmraw = __shfl_down(wgt, 1);
    const float wmv   = (lane < 62) ? wmraw : 0.f;          // weights[:,1:-1], 62 bins
    // telescoped weight-sum: sum wgt[1..62] = T_1 - T_63 (+O(62*EPS_T))
    const float p0   = __shfl(p, 0);
    const float p62  = __shfl(p, 62);
    const float wsum = p0 - p62;
    const float pad  = fmaxf(0.f, EPS_W - wsum);
    const float wadj = wmv + pad * (1.0f / 62.0f);
    const float wsp  = wsum + pad;
    const float pdf  = (lane < 62) ? (wadj / wsp) : 0.f;    // exact div: CDF path
    float ps = pdf;
#pragma unroll
    for (int off = 1; off < 64; off <<= 1) {               // inclusive sum scan (CDF path, keep __shfl)
        const float q = __shfl_up(ps, off);
        if (lane >= off) ps += q;
    }
    if (lane < 61)  sCdfw[lane + 1] = fminf(1.f, ps);      // cdf[1..61]
    if (lane == 61) sCdfw[0]  = 0.f;
    if (lane == 62) sCdfw[62] = 1.f;
    wsync();

    float zsv[2];
#pragma unroll
    for (int j = 0; j < 2; ++j) {
        const int f = lane * 2 + j;
        const float u = (float)f * ((1.0f - F32EPS) / 127.0f);
        int lo = 0, hi = 62;                               // cdf[0]=0<=u < 1=cdf[62]
        while (hi - lo > 1) {
            const int mid = (lo + hi) >> 1;
            if (sCdfw[mid] <= u) lo = mid; else hi = mid;
        }
        const float c0 = sCdfw[lo], c1 = sCdfw[lo + 1];
        const float den = c1 - c0;
        float tt = (den > 0.f) ? (u - c0) * frcp(den) : 0.f;
        tt = fminf(fmaxf(tt, 0.f), 1.f);
        const float za = zc(lo), zb = zc(lo + 1), zd = zc(lo + 2);
        const float bin0 = 0.5f * (za + zb), bin1 = 0.5f * (zb + zd);
        const float zs = fmaf(tt, bin1 - bin0, bin0);
        zsv[j] = zs;
        sZs[w][f] = zs;
    }
    wsync();   // sCdf reads done; sVal (same pool) may be written after this point

    // ---------------- fresh-sample MLP (2 samples/lane, f32) ----------------
    const v2f zA = mk2(zsv[0], zsv[0]), zB = mk2(zsv[1], zsv[1]);
    v2f a01 = mk2(bb0, bb1), a23 = mk2(bb2, bb3);
    v2f e01 = mk2(bb0, bb1), e23 = mk2(bb2, bb3);
#pragma unroll 2
    for (int i = 0; i < 16; ++i) {
        const float4 a4 = ((const float4*)sA[w])[i];
        const float4 b4 = ((const float4*)sB[w])[i];
        const float4 q0 = W2v[4 * i + 0], q1 = W2v[4 * i + 1];
        const float4 q2 = W2v[4 * i + 2], q3 = W2v[4 * i + 3];
        const v2f blo = mk2(b4.x, b4.y), bhi = mk2(b4.z, b4.w);
        const v2f alo = mk2(a4.x, a4.y), ahi = mk2(a4.z, a4.w);
        const v2f hAL = pmax0(pfma(zA, blo, alo)), hAH = pmax0(pfma(zA, bhi, ahi));
        const v2f hBL = pmax0(pfma(zB, blo, alo)), hBH = pmax0(pfma(zB, bhi, ahi));
        const v2f q0a = mk2(q0.x, q0.y), q0b = mk2(q0.z, q0.w);
        const v2f q1a = mk2(q1.x, q1.y), q1b = mk2(q1.z, q1.w);
        const v2f q2a = mk2(q2.x, q2.y), q2b = mk2(q2.z, q2.w);
        const v2f q3a = mk2(q3.x, q3.y), q3b = mk2(q3.z, q3.w);
        a01 = pfma(mk2(hAL.x, hAL.x), q0a, a01); a23 = pfma(mk2(hAL.x, hAL.x), q0b, a23);
        a01 = pfma(mk2(hAL.y, hAL.y), q1a, a01); a23 = pfma(mk2(hAL.y, hAL.y), q1b, a23);
        a01 = pfma(mk2(hAH.x, hAH.x), q2a, a01); a23 = pfma(mk2(hAH.x, hAH.x), q2b, a23);
        a01 = pfma(mk2(hAH.y, hAH.y), q3a, a01); a23 = pfma(mk2(hAH.y, hAH.y), q3b, a23);
        e01 = pfma(mk2(hBL.x, hBL.x), q0a, e01); e23 = pfma(mk2(hBL.x, hBL.x), q0b, e23);
        e01 = pfma(mk2(hBL.y, hBL.y), q1a, e01); e23 = pfma(mk2(hBL.y, hBL.y), q1b, e23);
        e01 = pfma(mk2(hBH.x, hBH.x), q2a, e01); e23 = pfma(mk2(hBH.x, hBH.x), q2b, e23);
        e01 = pfma(mk2(hBH.y, hBH.y), q3a, e01); e23 = pfma(mk2(hBH.y, hBH.y), q3b, e23);
    }
    const float r0s = sigm(a01.x), g0s = sigm(a01.y), b0s = sigm(a23.x), s0 = fmaxf(a23.y, 0.f);
    const float r1s = sigm(e01.x), g1s = sigm(e01.y), b1s = sigm(e23.x), s1 = fmaxf(e23.y, 0.f);

    // ---------------- merge (LDS single source of truth -> provable bijection) --
    {   // coarse element: pos = lane + count(samples < z); carry coarse MLP values
        int lo = 0, hi = 128;
        while (lo < hi) { const int mid = (lo + hi) >> 1; if (sZs[w][mid] < z) lo = mid + 1; else hi = mid; }
        sZf[w][lane + lo] = z;
        float4 cv; cv.x = r; cv.y = g; cv.z = bl; cv.w = sig;
        sValw[lane + lo] = cv;
    }
#pragma unroll
    for (int j = 0; j < 2; ++j) {   // sample element: pos = idx + count(coarse <= bv)
        const float bv = zsv[j];
        const int f = lane * 2 + j;
        int lo = 0, hi = 64;
        while (lo < hi) { const int mid = (lo + hi) >> 1; if (sZc[w][mid] <= bv) lo = mid + 1; else hi = mid; }
        sZf[w][f + lo] = bv;
        float4 cv;
        if (j == 0) { cv.x = r0s; cv.y = g0s; cv.z = b0s; cv.w = s0; }
        else        { cv.x = r1s; cv.y = g1s; cv.z = b1s; cv.w = s1; }
        sValw[f + lo] = cv;
    }
    wsync();

    // ---------------- fine volrender: 3 positions/lane ----------------
    const float zf0 = sZf[w][3 * lane + 0];
    const float zf1 = sZf[w][3 * lane + 1];
    const float zf2 = sZf[w][3 * lane + 2];
    const float zn2 = sZf[w][min(3 * lane + 3, 191)];      // lane63 value unused
    const float4 c4a = sValw[3 * lane + 0];
    const float4 c4b = sValw[3 * lane + 1];
    const float4 c4c = sValw[3 * lane + 2];

    const float d0 = (zf1 - zf0) * norm, d1 = (zf2 - zf1) * norm, d2 = (zn2 - zf2) * norm;
    const float al0 = 1.f - __expf(-c4a.w * d0);
    const float al1 = 1.f - __expf(-c4b.w * d1);
    const float al2 = (lane < 63) ? (1.f - __expf(-c4c.w * d2)) : 1.f;
    const float t0v = 1.f - al0 + EPS_T, t1v = 1.f - al1 + EPS_T, t2v = 1.f - al2 + EPS_T;

    // fine transmittance scan — smooth path -> DPP (VALU pipe)
    const float lp = pscan(t0v * t1v * t2v);
    float ex = __shfl_up(lp, 1);
    if (lane == 0) ex = 1.f;
    const float tr1 = ex * t0v, tr2 = tr1 * t1v;
    const float w0 = al0 * ex, w1 = al1 * tr1, w2 = al2 * tr2;

    // fine acc == 1 + O(192*EPS_T) -> white-bkgd term ~0; DPP sums, lane 63
    const float fr = redsum63(fmaf(w0, c4a.x, fmaf(w1, c4b.x, w2 * c4c.x)));
    const float fg = redsum63(fmaf(w0, c4a.y, fmaf(w1, c4b.y, w2 * c4c.y)));
    const float fb = redsum63(fmaf(w0, c4a.z, fmaf(w1, c4b.z, w2 * c4c.z)));
    const float fd = redsum63(fmaf(w0, zf0,   fmaf(w1, zf1,   w2 * zf2)));

    if (lane == 63) {
        float* po = out + (size_t)ray * 8;
        po[0] = sr; po[1] = sg; po[2] = sb; po[3] = sd;
        po[4] = fr; po[5] = fg; po[6] = fb; po[7] = fd;
    }
}

extern "C" void kernel_launch(void* const* d_in, const int* in_sizes, int n_in,
                              void* d_out, int out_size, void* d_ws, size_t ws_size,
                              hipStream_t stream) {
    const float* ro = (const float*)d_in[0];
    const float* rd = (const float*)d_in[1];
    const float* W1 = (const float*)d_in[2];
    const float* b1 = (const float*)d_in[3];
    const float* W2 = (const float*)d_in[4];
    const float* b2 = (const float*)d_in[5];
    float* out = (float*)d_out;
    nerf_kernel<<<dim3(RAYS / 4), dim3(256), 0, stream>>>(ro, rd, W1, b1, W2, b2, out);
}